// Round 6
// baseline (202.887 us; speedup 1.0000x reference)
//
#include <hip/hip_runtime.h>
#include <math.h>

namespace {

constexpr int kB = 4;
constexpr int kL = 4096;
constexpr int kD = 1024;
constexpr int kN = 64;
constexpr int kM = kB * kL;               // 16384 rows (b*L + l)
constexpr size_t kBLN = (size_t)kM * kN;  // 1,048,576 floats per u-buffer
constexpr int kSplit = 4;                 // K-split for GEMM1
constexpr int kKRange = kD / kSplit;      // 256
constexpr int kChunks = 64;               // scan chunks per sequence
constexpr int kChunkLen = kL / kChunks;   // 64 steps per chunk

// ---------------------------------------------------------------------------
// GEMM1: u[m][n] = sum_d x[m][d] * W_in[n][d]   (partial over K-split range)
// grid (kM/64, kSplit), block 64 (one wave). 64x64 tile, 8x8 micro.
// Model: 4 waves/CU; per k-step 4x ds_read_b128 (~12cyc) x4 waves = 192
// LDS-cyc/CU vs 128 VALU-cyc -> expect LDS-return-bound (~20us) unless
// broadcast B-reads are charged at unique-data rate (then ~14us, VALU-bound).
// ---------------------------------------------------------------------------
__global__ __launch_bounds__(64) void k_gemm_in(const float* __restrict__ x,
                                                const float* __restrict__ Win,
                                                float* __restrict__ upart) {
  __shared__ __align__(16) float As[64][68];  // [k][m], pad 4 keeps 16B align
  __shared__ __align__(16) float Bs[64][68];  // [k][n]
  const int t = threadIdx.x;
  const int m_blk = blockIdx.x * 64;
  const int z = blockIdx.y;

  const int tm = t & 7;
  const int tn = t >> 3;
  const int m0 = tm * 8;
  const int n0 = tn * 8;

  float acc[8][8];
#pragma unroll
  for (int i = 0; i < 8; ++i)
#pragma unroll
    for (int j = 0; j < 8; ++j) acc[i][j] = 0.0f;

  for (int kc = 0; kc < kKRange; kc += 64) {
    const int k0 = z * kKRange + kc;
    // Transpose-on-load: lane t owns k=t; gather 4 consecutive m rows and
    // store one float4 at As[k][m4] -> conflict-free ds_write_b128.
#pragma unroll
    for (int i = 0; i < 16; ++i) {
      const int m4 = i * 4;
      const float* src = &x[(size_t)(m_blk + m4) * kD + k0 + t];
      float4 v = make_float4(src[0], src[kD], src[2 * kD], src[3 * kD]);
      *reinterpret_cast<float4*>(&As[t][m4]) = v;
    }
#pragma unroll
    for (int i = 0; i < 16; ++i) {
      const int n4 = i * 4;
      const float* src = &Win[(size_t)n4 * kD + k0 + t];
      float4 v = make_float4(src[0], src[kD], src[2 * kD], src[3 * kD]);
      *reinterpret_cast<float4*>(&Bs[t][n4]) = v;
    }
    __syncthreads();

#pragma unroll 4
    for (int k = 0; k < 64; ++k) {
      float4 a0 = *reinterpret_cast<const float4*>(&As[k][m0]);
      float4 a1 = *reinterpret_cast<const float4*>(&As[k][m0 + 4]);
      float4 b0 = *reinterpret_cast<const float4*>(&Bs[k][n0]);
      float4 b1 = *reinterpret_cast<const float4*>(&Bs[k][n0 + 4]);
      float a[8] = {a0.x, a0.y, a0.z, a0.w, a1.x, a1.y, a1.z, a1.w};
      float b[8] = {b0.x, b0.y, b0.z, b0.w, b1.x, b1.y, b1.z, b1.w};
#pragma unroll
      for (int i = 0; i < 8; ++i)
#pragma unroll
        for (int j = 0; j < 8; ++j) acc[i][j] = fmaf(a[i], b[j], acc[i][j]);
    }
    __syncthreads();
  }

  float* up = upart + (size_t)z * kBLN;
#pragma unroll
  for (int i = 0; i < 8; ++i) {
    const size_t o = (size_t)(m_blk + m0 + i) * kN + n0;
    *reinterpret_cast<float4*>(&up[o]) =
        make_float4(acc[i][0], acc[i][1], acc[i][2], acc[i][3]);
    *reinterpret_cast<float4*>(&up[o + 4]) =
        make_float4(acc[i][4], acc[i][5], acc[i][6], acc[i][7]);
  }
}

// ---------------------------------------------------------------------------
// ZOH discretization helper (per lane n)
// ---------------------------------------------------------------------------
__device__ __forceinline__ void zoh(const float* __restrict__ logA,
                                    const float* __restrict__ logdt, int n,
                                    float& A, float& dt, float& Abar) {
  dt = expf(logdt[0]);
  A = -expf(logA[n]);
  Abar = expf(A * dt);
}

__device__ __forceinline__ float zoh_bbar(float A, float dt, float Abar,
                                          float Bp) {
  const bool small = fabsf(A) < 1e-6f;
  const float denom = small ? 1.0f : A;
  float frac = (Abar - 1.0f) / denom;
  frac = small ? dt : frac;
  return frac * Bp;
}

// ---------------------------------------------------------------------------
// Scan phase 1: per chunk, sum the 4 u-partials, pre-scale by Bbar (stored
// in-place over partial 0), and compute the chunk-local final state.
// grid (kChunks, kB), block 64 (lane = n). Unroll 8: ~8KB/stream in flight
// (256 streams need ~9.4KB each to reach 6.3TB/s at 900cy HBM latency).
// ---------------------------------------------------------------------------
__global__ __launch_bounds__(64) void k_scan_local(
    const float* __restrict__ logA, const float* __restrict__ Bparam,
    const float* __restrict__ logdt, float* __restrict__ ws) {
  const int n = threadIdx.x;
  const int c = blockIdx.x;
  const int b = blockIdx.y;
  float A, dt, Abar;
  zoh(logA, logdt, n, A, dt, Abar);
  const float Bbar = zoh_bbar(A, dt, Abar, Bparam[n]);

  float* hloc = ws + 4 * kBLN;  // [b][chunk][n]
  const size_t base = ((size_t)b * kL + (size_t)c * kChunkLen) * kN + n;

  float h = 0.0f;
#pragma unroll 8
  for (int s = 0; s < kChunkLen; ++s) {
    const size_t idx = base + (size_t)s * kN;
    const float uu = ws[idx] + ws[idx + kBLN] + ws[idx + 2 * kBLN] +
                     ws[idx + 3 * kBLN];
    const float ub = uu * Bbar;
    h = fmaf(h, Abar, ub);
    ws[idx] = ub;  // overwrite partial 0 with Bbar-scaled summed u
  }
  hloc[((size_t)b * kChunks + c) * kN + n] = h;
}

// ---------------------------------------------------------------------------
// Scan phase 2 (fused combine+apply): block (c,b) first recomputes its own
// chunk-init state via the Horner prefix over hloc[0..c-1] (<=63 independent
// L2-resident loads, prefetch distance 2, + <=63 dependent fmas ~0.2us),
// then replays its chunk writing y = h*C into the partial-1 region.
// Numerically identical to a separate combine kernel (same Horner order).
// grid (kChunks, kB), block 64.
// ---------------------------------------------------------------------------
__global__ __launch_bounds__(64) void k_scan_apply(
    const float* __restrict__ logA, const float* __restrict__ Cparam,
    const float* __restrict__ logdt, float* __restrict__ ws) {
  const int n = threadIdx.x;
  const int c = blockIdx.x;
  const int b = blockIdx.y;
  float A, dt, Abar;
  zoh(logA, logdt, n, A, dt, Abar);
  const float C = Cparam[n];
  const float AbarC = expf(A * dt * (float)kChunkLen);  // Abar^kChunkLen

  const float* hloc = ws + 4 * kBLN;  // [b][chunk][n]
  const size_t hbase = (size_t)b * kChunks * kN + n;

  // Horner prefix: h_init = sum_{j<c} hloc[j] * AbarC^(c-1-j)
  float h = 0.0f;
  if (c > 0) {
    float p0 = hloc[hbase];  // j=0
    float p1 = (c > 1) ? hloc[hbase + kN] : 0.0f;
    for (int j = 0; j < c; ++j) {
      const float cur = p0;
      p0 = p1;
      p1 = (j + 2 < c) ? hloc[hbase + (size_t)(j + 2) * kN] : 0.0f;
      h = fmaf(h, AbarC, cur);
    }
  }

  float* ybuf = ws + kBLN;
  const size_t base = ((size_t)b * kL + (size_t)c * kChunkLen) * kN + n;
#pragma unroll 8
  for (int s = 0; s < kChunkLen; ++s) {
    const size_t idx = base + (size_t)s * kN;
    h = fmaf(h, Abar, ws[idx]);  // ws[idx] holds Bbar-scaled u
    ybuf[idx] = h * C;
  }
}

// ---------------------------------------------------------------------------
// GEMM2: out[m][d] = sum_n y[m][n] * W_out[d][n]
// grid (kM/64, kD/128), block 128 (2 waves). Tile 64x128, 8x8 micro.
// ---------------------------------------------------------------------------
__global__ __launch_bounds__(128) void k_gemm_out(
    const float* __restrict__ y, const float* __restrict__ Wout,
    float* __restrict__ out) {
  __shared__ __align__(16) float Ys[64][68];   // [k][m]
  __shared__ __align__(16) float Ws[64][132];  // [k][d]
  const int t = threadIdx.x;
  const int m_blk = blockIdx.x * 64;
  const int d_blk = blockIdx.y * 128;

  const int k = t & 63;
  const int w = t >> 6;  // wave id 0..1

  // y tile: 64 rows x 64 k. 16 row-groups of 4, two waves interleave.
#pragma unroll
  for (int i = 0; i < 8; ++i) {
    const int m4 = (i * 2 + w) * 4;
    const float* src = &y[(size_t)(m_blk + m4) * kN + k];
    *reinterpret_cast<float4*>(&Ys[k][m4]) =
        make_float4(src[0], src[kN], src[2 * kN], src[3 * kN]);
  }
  // W_out tile: 128 rows x 64 k. 32 row-groups of 4.
#pragma unroll
  for (int i = 0; i < 16; ++i) {
    const int d4 = (i * 2 + w) * 4;
    const float* src = &Wout[(size_t)(d_blk + d4) * kN + k];
    *reinterpret_cast<float4*>(&Ws[k][d4]) =
        make_float4(src[0], src[kN], src[2 * kN], src[3 * kN]);
  }
  __syncthreads();

  const int tm = t & 7;
  const int tn = t >> 3;  // 0..15
  const int m0 = tm * 8;
  const int n0 = tn * 8;

  float acc[8][8];
#pragma unroll
  for (int i = 0; i < 8; ++i)
#pragma unroll
    for (int j = 0; j < 8; ++j) acc[i][j] = 0.0f;

#pragma unroll 4
  for (int kk = 0; kk < 64; ++kk) {
    float4 a0 = *reinterpret_cast<const float4*>(&Ys[kk][m0]);
    float4 a1 = *reinterpret_cast<const float4*>(&Ys[kk][m0 + 4]);
    float4 b0 = *reinterpret_cast<const float4*>(&Ws[kk][n0]);
    float4 b1 = *reinterpret_cast<const float4*>(&Ws[kk][n0 + 4]);
    float a[8] = {a0.x, a0.y, a0.z, a0.w, a1.x, a1.y, a1.z, a1.w};
    float b[8] = {b0.x, b0.y, b0.z, b0.w, b1.x, b1.y, b1.z, b1.w};
#pragma unroll
    for (int i = 0; i < 8; ++i)
#pragma unroll
      for (int j = 0; j < 8; ++j) acc[i][j] = fmaf(a[i], b[j], acc[i][j]);
  }

#pragma unroll
  for (int i = 0; i < 8; ++i) {
    const size_t o = (size_t)(m_blk + m0 + i) * kD + d_blk + n0;
    *reinterpret_cast<float4*>(&out[o]) =
        make_float4(acc[i][0], acc[i][1], acc[i][2], acc[i][3]);
    *reinterpret_cast<float4*>(&out[o + 4]) =
        make_float4(acc[i][4], acc[i][5], acc[i][6], acc[i][7]);
  }
}

}  // namespace

// ---------------------------------------------------------------------------
// Workspace layout (floats):
//   [0*kBLN, 4*kBLN)  : 4 u-partials from GEMM1.
//                       partial 0 is overwritten in-place by scan phase 1
//                       with Bbar-scaled summed u; partial 1's region is
//                       overwritten by phase 2 with y = h*C.
//   [4*kBLN, +16384)  : hloc (kB * kChunks * kN)
// Total: 16 MiB + 64 KiB.
// ---------------------------------------------------------------------------
extern "C" void kernel_launch(void* const* d_in, const int* in_sizes, int n_in,
                              void* d_out, int out_size, void* d_ws,
                              size_t ws_size, hipStream_t stream) {
  const float* x = (const float*)d_in[0];
  const float* Win = (const float*)d_in[1];
  const float* Wout = (const float*)d_in[2];
  const float* logA = (const float*)d_in[3];
  const float* Bparam = (const float*)d_in[4];
  const float* Cparam = (const float*)d_in[5];
  const float* logdt = (const float*)d_in[6];
  float* out = (float*)d_out;
  float* ws = (float*)d_ws;

  k_gemm_in<<<dim3(kM / 64, kSplit), 64, 0, stream>>>(x, Win, ws);
  k_scan_local<<<dim3(kChunks, kB), 64, 0, stream>>>(logA, Bparam, logdt, ws);
  k_scan_apply<<<dim3(kChunks, kB), 64, 0, stream>>>(logA, Cparam, logdt, ws);
  k_gemm_out<<<dim3(kM / 64, kD / 128), 128, 0, stream>>>(ws + kBLN, Wout, out);
}